// Round 7
// baseline (586.443 us; speedup 1.0000x reference)
//
#include <hip/hip_runtime.h>

// Quadtree attention forward, 3 levels. B=4, C=128, nh=8, d=16, topks=(16,8,8).
// Round 7: coarse = R5 barrier-free TOK structure + folded reductions +
// deferred softmax normalization; k0/v0/k1/v1 transposes fused into the coarse
// launch as interleaved blocks (overlap memory-bound transpose with
// VALU-bound coarse); mid/fine = R5 forms (no q transposes).

#define DEV static __device__ __forceinline__

DEV float wave_max(float v){
  #pragma unroll
  for(int o=32;o>0;o>>=1) v = fmaxf(v, __shfl_xor(v,o,64));
  return v;
}
DEV float wave_sum(float v){
  #pragma unroll
  for(int o=32;o>0;o>>=1) v += __shfl_xor(v,o,64);
  return v;
}
DEV float half_max(float v){
  #pragma unroll
  for(int o=16;o>0;o>>=1) v = fmaxf(v, __shfl_xor(v,o,64));
  return v;
}
DEV float half_sum(float v){
  #pragma unroll
  for(int o=16;o>0;o>>=1) v += __shfl_xor(v,o,64);
  return v;
}
DEV void wave_argmax(float& v, int& idx){
  #pragma unroll
  for(int o=32;o>0;o>>=1){
    float ov = __shfl_xor(v,o,64);
    int   oi = __shfl_xor(idx,o,64);
    if (ov > v || (ov == v && oi < idx)) { v = ov; idx = oi; }
  }
}

// masked local top-4 scan (ascending c, strict > => tie keeps lowest c)
DEV void scan4(const float (&sc)[16], unsigned &rem, float (&tv)[4], int (&tc)[4]){
  #pragma unroll
  for(int t=0;t<4;t++){
    float bv=-1e30f; int bc=0;
    #pragma unroll
    for(int c=0;c<16;c++){
      const bool ok = (((rem>>c)&1u)==0u) && (sc[c] > bv);
      bv = ok ? sc[c] : bv;
      bc = ok ? c : bc;
    }
    tv[t]=bv; tc[t]=bc; rem |= (1u<<bc);
  }
}

// top-16 for two queries, interleaved rounds; lane holds sc[c] for s=c*64+lane.
// ties -> lowest s. Non-destructive on sc. (R5-proven version)
DEV void top16_pair(const float (&sc0)[16], const float (&sc1)[16], int lane,
                    int &cap0, int &cap1){
  unsigned rem0=0u, rem1=0u;
  float tv0[4], tv1[4]; int tc0[4], tc1[4];
  scan4(sc0, rem0, tv0, tc0);
  scan4(sc1, rem1, tv1, tc1);
  cap0=0; cap1=0;
  #pragma unroll 1
  for(int r=0;r<16;r++){
    const float M0 = wave_max(tv0[0]);
    const float M1 = wave_max(tv1[0]);
    const unsigned long long k0 = __ballot(tv0[0]==M0);
    const unsigned long long k1 = __ballot(tv1[0]==M1);
    int wl0 = (int)__ffsll(k0)-1, ws0;
    int wl1 = (int)__ffsll(k1)-1, ws1;
    if (__popcll(k0)==1){ ws0 = __shfl(tc0[0], wl0)*64 + wl0; }
    else {
      int sel = (tv0[0]==M0) ? (tc0[0]*64+lane) : 0x7fffffff;
      #pragma unroll
      for(int o=32;o>0;o>>=1) sel = min(sel, __shfl_xor(sel,o,64));
      ws0 = sel; wl0 = ws0 & 63;
    }
    if (__popcll(k1)==1){ ws1 = __shfl(tc1[0], wl1)*64 + wl1; }
    else {
      int sel = (tv1[0]==M1) ? (tc1[0]*64+lane) : 0x7fffffff;
      #pragma unroll
      for(int o=32;o>0;o>>=1) sel = min(sel, __shfl_xor(sel,o,64));
      ws1 = sel; wl1 = ws1 & 63;
    }
    cap0 = (lane==r) ? ws0 : cap0;
    cap1 = (lane==r) ? ws1 : cap1;
    if (lane==wl0){
      tv0[0]=tv0[1]; tc0[0]=tc0[1];
      tv0[1]=tv0[2]; tc0[1]=tc0[2];
      tv0[2]=tv0[3]; tc0[2]=tc0[3];
      tv0[3]=-1e30f; tc0[3]=0;
      if (tv0[0] < -1e29f) scan4(sc0, rem0, tv0, tc0);
    }
    if (lane==wl1){
      tv1[0]=tv1[1]; tc1[0]=tc1[1];
      tv1[1]=tv1[2]; tc1[1]=tc1[2];
      tv1[2]=tv1[3]; tc1[2]=tc1[3];
      tv1[3]=-1e30f; tc1[3]=0;
      if (tv1[0] < -1e29f) scan4(sc1, rem1, tv1, tc1);
    }
  }
}

// fold 16 accumulators over 64 lanes: returns partial for dd=lane&15 summed
// over the 16 lanes sharing lane&15's low-4-bit orbit (15 shfl). Destroys a.
DEV float fold16(float (&a)[16], int lane){
  #pragma unroll
  for(int st=0; st<4; st++){
    const int o = 1<<st, nh = 8>>st;
    const int b = (lane>>st)&1;
    #pragma unroll
    for(int i=0;i<nh;i++){
      const float x = a[2*i], y = a[2*i+1];
      const float send = b ? x : y;
      const float keep = b ? y : x;
      a[i] = keep + __shfl_xor(send, o, 64);
    }
  }
  return a[0];
}

// ---------------- coarse block body (2 queries/wave, no LDS/barriers) ------
template<bool TOK>
DEV void coarse_block(int cid, int tid,
    const float* __restrict__ q, const float* __restrict__ k, const float* __restrict__ v,
    const float* __restrict__ ktok, const float* __restrict__ vtok,
    float* __restrict__ msg0, int* __restrict__ topk0)
{
  const int wid = tid>>6, lane = tid&63;
  const int gq0 = __builtin_amdgcn_readfirstlane((cid*4 + wid)*2);
  const int bh = gq0>>10, l0 = gq0&1023;

  const float* qb = q + (size_t)bh*16384;
  float qv0[16], qv1[16];
  #pragma unroll
  for(int dd=0;dd<16;dd++){ qv0[dd]=qb[dd*1024+l0]*0.25f; qv1[dd]=qb[dd*1024+l0+1]*0.25f; }

  // ---- pass 1: scores (s = c*64 + lane), 0.25 pre-folded into q ----
  float sc0[16], sc1[16];
  #pragma unroll
  for(int c=0;c<16;c++){
    const int s = c*64 + lane;
    float kr[16];
    if constexpr (TOK){
      const float4* kp = (const float4*)(ktok + ((size_t)bh*1024 + s)*16);
      float4 x0=kp[0], x1=kp[1], x2=kp[2], x3=kp[3];
      kr[0]=x0.x; kr[1]=x0.y; kr[2]=x0.z; kr[3]=x0.w;
      kr[4]=x1.x; kr[5]=x1.y; kr[6]=x1.z; kr[7]=x1.w;
      kr[8]=x2.x; kr[9]=x2.y; kr[10]=x2.z; kr[11]=x2.w;
      kr[12]=x3.x; kr[13]=x3.y; kr[14]=x3.z; kr[15]=x3.w;
    } else {
      const float* kb = k + (size_t)bh*16384 + s;
      #pragma unroll
      for(int dd=0;dd<16;dd++) kr[dd] = kb[dd*1024];
    }
    float a0=0.f, a1=0.f;
    #pragma unroll
    for(int dd=0;dd<16;dd++){ a0=fmaf(qv0[dd],kr[dd],a0); a1=fmaf(qv1[dd],kr[dd],a1); }
    sc0[c]=a0; sc1[c]=a1;
  }

  // ---- top-16 on raw scores (exp monotone) ----
  int cap0, cap1;
  top16_pair(sc0, sc1, lane, cap0, cap1);
  if (lane < 16){
    topk0[(size_t)gq0*16 + lane]     = cap0;
    topk0[(size_t)(gq0+1)*16 + lane] = cap1;
  }

  // ---- folded max over both queries (7 shfl) ----
  float m0l=-1e30f, m1l=-1e30f;
  #pragma unroll
  for(int c=0;c<16;c++){ m0l=fmaxf(m0l,sc0[c]); m1l=fmaxf(m1l,sc1[c]); }
  float m0, m1;
  {
    float t  = (lane&16) ? m1l : m0l;
    float sd = (lane&16) ? m0l : m1l;
    t = fmaxf(t, __shfl_xor(sd,16,64));
    t = fmaxf(t, __shfl_xor(t,32,64));
    t = fmaxf(t, __shfl_xor(t, 8,64));
    t = fmaxf(t, __shfl_xor(t, 4,64));
    t = fmaxf(t, __shfl_xor(t, 2,64));
    t = fmaxf(t, __shfl_xor(t, 1,64));
    const float to = __shfl_xor(t,16,64);
    m0 = (lane&16) ? to : t;
    m1 = (lane&16) ? t  : to;
  }

  // ---- exp in place; folded sum -> inv for this lane's bit4-query ----
  float s0l=0.f, s1l=0.f;
  #pragma unroll
  for(int c=0;c<16;c++){
    sc0[c]=__expf(sc0[c]-m0); s0l+=sc0[c];
    sc1[c]=__expf(sc1[c]-m1); s1l+=sc1[c];
  }
  float inv;
  {
    float t  = (lane&16) ? s1l : s0l;
    float sd = (lane&16) ? s0l : s1l;
    t += __shfl_xor(sd,16,64);
    t += __shfl_xor(t,32,64);
    t += __shfl_xor(t, 8,64);
    t += __shfl_xor(t, 4,64);
    t += __shfl_xor(t, 2,64);
    t += __shfl_xor(t, 1,64);
    inv = 1.0f / t;
  }

  // ---- pass 2: AV with raw exp weights ----
  float acc0[16], acc1[16];
  #pragma unroll
  for(int dd=0;dd<16;dd++){ acc0[dd]=0.f; acc1[dd]=0.f; }
  #pragma unroll
  for(int c=0;c<16;c++){
    const int s = c*64 + lane;
    float vr[16];
    if constexpr (TOK){
      const float4* vp = (const float4*)(vtok + ((size_t)bh*1024 + s)*16);
      float4 x0=vp[0], x1=vp[1], x2=vp[2], x3=vp[3];
      vr[0]=x0.x; vr[1]=x0.y; vr[2]=x0.z; vr[3]=x0.w;
      vr[4]=x1.x; vr[5]=x1.y; vr[6]=x1.z; vr[7]=x1.w;
      vr[8]=x2.x; vr[9]=x2.y; vr[10]=x2.z; vr[11]=x2.w;
      vr[12]=x3.x; vr[13]=x3.y; vr[14]=x3.z; vr[15]=x3.w;
    } else {
      const float* vb = v + (size_t)bh*16384 + s;
      #pragma unroll
      for(int dd=0;dd<16;dd++) vr[dd] = vb[dd*1024];
    }
    const float p0c = sc0[c], p1c = sc1[c];
    #pragma unroll
    for(int dd=0;dd<16;dd++){ acc0[dd]=fmaf(p0c,vr[dd],acc0[dd]); acc1[dd]=fmaf(p1c,vr[dd],acc1[dd]); }
  }

  // ---- folded reduction: 32 shfl total; ends at dd=lane&15, query=bit4 ----
  const float a0f = fold16(acc0, lane);
  const float a1f = fold16(acc1, lane);
  {
    const float mine = (lane&16) ? a1f : a0f;
    const float send = (lane&16) ? a0f : a1f;
    float tot = mine + __shfl_xor(send,16,64);
    tot += __shfl_xor(tot,32,64);
    tot *= inv;                       // deferred normalization
    if (lane < 32) msg0[(size_t)(gq0 + (lane>>4))*16 + (lane&15)] = tot;
  }
}

// -------- pre: transpose k2,v2 -> token-major (256 blocks, ~5us) -----------
__global__ __launch_bounds__(256) void k_pre(
    const float* __restrict__ k2, const float* __restrict__ v2,
    float* __restrict__ ktok2, float* __restrict__ vtok2)
{
  const int blk = blockIdx.x;
  const float* src = (blk<128) ? k2 : v2;
  float* dst = (blk<128) ? ktok2 : vtok2;
  const int id = (blk & 127)*256 + threadIdx.x;
  const int s = id & 1023, bh = id >> 10;
  const float* sp = src + ((size_t)bh<<14) + s;
  float r[16];
  #pragma unroll
  for(int dd=0;dd<16;dd++) r[dd] = sp[(size_t)dd<<10];
  float4* dp = (float4*)(dst + (size_t)id*16);
  dp[0] = make_float4(r[0],r[1],r[2],r[3]);
  dp[1] = make_float4(r[4],r[5],r[6],r[7]);
  dp[2] = make_float4(r[8],r[9],r[10],r[11]);
  dp[3] = make_float4(r[12],r[13],r[14],r[15]);
}

// -------- mega: interleaved coarse blocks + k0/v0/k1/v1 transpose blocks ----
// idx<8192: even -> coarse (idx>>1), odd -> transpose (idx>>1);
// idx>=8192 -> transpose (4096 + idx-8192). Transposes feed mid/fine only.
__global__ __launch_bounds__(256) void k_mega(
    const float* __restrict__ q2, const float* __restrict__ k2, const float* __restrict__ v2,
    const float* __restrict__ ktok2, const float* __restrict__ vtok2,
    float* __restrict__ msg0, int* __restrict__ topk0,
    const float* __restrict__ k0, const float* __restrict__ v0,
    const float* __restrict__ k1, const float* __restrict__ v1,
    float* __restrict__ ktok0, float* __restrict__ vtok0,
    float* __restrict__ ktok1, float* __restrict__ vtok1)
{
  const int idx = blockIdx.x;
  int tb;
  if (idx < 8192){
    if ((idx & 1) == 0){
      coarse_block<true>(idx>>1, threadIdx.x, q2,k2,v2, ktok2,vtok2, msg0, topk0);
      return;
    }
    tb = idx>>1;
  } else {
    tb = 4096 + (idx - 8192);
  }
  const float* src; float* dst; int lgS, base;
  if      (tb < 2048){ lgS=14; src=k0; dst=ktok0; base=0; }
  else if (tb < 4096){ lgS=14; src=v0; dst=vtok0; base=2048; }
  else if (tb < 4608){ lgS=12; src=k1; dst=ktok1; base=4096; }
  else               { lgS=12; src=v1; dst=vtok1; base=4608; }
  const int id = (tb-base)*256 + threadIdx.x;
  const int s = id & ((1<<lgS)-1), bh = id >> lgS;
  const float* sp = src + ((size_t)bh<<(lgS+4)) + s;
  float r[16];
  #pragma unroll
  for(int dd=0;dd<16;dd++) r[dd] = sp[(size_t)dd<<lgS];
  float4* dp = (float4*)(dst + (size_t)id*16);
  dp[0] = make_float4(r[0],r[1],r[2],r[3]);
  dp[1] = make_float4(r[4],r[5],r[6],r[7]);
  dp[2] = make_float4(r[8],r[9],r[10],r[11]);
  dp[3] = make_float4(r[12],r[13],r[14],r[15]);
}

__global__ __launch_bounds__(256) void k_coarse_fb(
    const float* __restrict__ q, const float* __restrict__ k, const float* __restrict__ v,
    float* __restrict__ msg0, int* __restrict__ topk0)
{
  coarse_block<false>(blockIdx.x, threadIdx.x, q,k,v, nullptr,nullptr, msg0, topk0);
}

// ---------------- mid: K=64 gathered children, 4 queries/group, top-8 -------
template<bool TOK>
__global__ __launch_bounds__(256) void k_mid(
    const float* __restrict__ q, const float* __restrict__ k, const float* __restrict__ v,
    const float* __restrict__ ktok, const float* __restrict__ vtok,
    const int* __restrict__ topk0, float* __restrict__ msg1, int* __restrict__ topk1)
{
  __shared__ float s_v[4][16][66];
  __shared__ float s_e[4][4][65];
  __shared__ float s_k[TOK?1:4][16][66];
  const int tid = threadIdx.x, wid = tid>>6, lane = tid&63;
  const int slot = __builtin_amdgcn_readfirstlane(blockIdx.x*4 + wid);
  const int l = slot & 1023, bh = slot >> 10;
  const int gy = l>>5, gx = l&31;
  const float* qb = q + (size_t)bh*65536;

  float kv[16];
  if constexpr (TOK){
    const int w = lane>>2, c = lane&3;
    const int widx = topk0[(size_t)slot*16 + w];
    const int pos = (2*(widx>>5) + (c>>1))*64 + 2*(widx&31) + (c&1);
    const float4* kp = (const float4*)(ktok + ((size_t)bh*4096 + pos)*16);
    float4 x0=kp[0], x1=kp[1], x2=kp[2], x3=kp[3];
    kv[0]=x0.x; kv[1]=x0.y; kv[2]=x0.z; kv[3]=x0.w;
    kv[4]=x1.x; kv[5]=x1.y; kv[6]=x1.z; kv[7]=x1.w;
    kv[8]=x2.x; kv[9]=x2.y; kv[10]=x2.z; kv[11]=x2.w;
    kv[12]=x3.x; kv[13]=x3.y; kv[14]=x3.z; kv[15]=x3.w;
    const float4* vp = (const float4*)(vtok + ((size_t)bh*4096 + pos)*16);
    float4 y0=vp[0], y1=vp[1], y2=vp[2], y3=vp[3];
    s_v[wid][0][lane]=y0.x;  s_v[wid][1][lane]=y0.y;  s_v[wid][2][lane]=y0.z;  s_v[wid][3][lane]=y0.w;
    s_v[wid][4][lane]=y1.x;  s_v[wid][5][lane]=y1.y;  s_v[wid][6][lane]=y1.z;  s_v[wid][7][lane]=y1.w;
    s_v[wid][8][lane]=y2.x;  s_v[wid][9][lane]=y2.y;  s_v[wid][10][lane]=y2.z; s_v[wid][11][lane]=y2.w;
    s_v[wid][12][lane]=y3.x; s_v[wid][13][lane]=y3.y; s_v[wid][14][lane]=y3.z; s_v[wid][15][lane]=y3.w;
  } else {
    const int kvsel = lane>>5, rr = lane&31, w = rr>>1, cy = rr&1;
    const int widx = topk0[(size_t)slot*16 + w];
    const int base = (2*(widx>>5) + cy)*64 + 2*(widx&31);
    const float* src = (kvsel ? v : k) + (size_t)bh*65536;
    float* dst = kvsel ? &s_v[wid][0][0] : &s_k[wid][0][0];
    const int key0 = w*4 + cy*2;
    #pragma unroll
    for(int dd=0;dd<16;dd++){
      const float2 f2 = *(const float2*)(src + dd*4096 + base);
      *(float2*)(dst + dd*66 + key0) = f2;
    }
    #pragma unroll
    for(int dd=0;dd<16;dd++) kv[dd] = s_k[wid][dd][lane];
  }

  // ---- scores + softmax (lane = gathered key) ----
  #pragma unroll
  for(int t=0;t<4;t++){
    const int qp = (2*gy + (t>>1))*64 + 2*gx + (t&1);
    float a = 0.f;
    #pragma unroll
    for(int dd=0;dd<16;dd++) a = fmaf(qb[dd*4096 + qp], kv[dd], a);
    a *= 0.25f;
    const float m = wave_max(a);
    const float e = __expf(a - m);
    const float s = wave_sum(e);
    s_e[wid][t][lane] = e / s;
  }

  // ---- top-8: group g (16 lanes) handles t=g; lane j owns keys j*4+e ----
  const int g = lane>>4, j = lane&15;
  {
    const int wj_ = topk0[(size_t)slot*16 + j];
    const int tyj = wj_>>5, txj = wj_&31;
    int posj[4];
    #pragma unroll
    for(int e=0;e<4;e++) posj[e] = (2*tyj + (e>>1))*64 + 2*txj + (e&1);
    float ev[4];
    #pragma unroll
    for(int e=0;e<4;e++) ev[e] = s_e[wid][g][j*4+e];
    int cap = 0;
    for(int r=0;r<8;r++){
      float lv = ev[0]; int le = 0;
      #pragma unroll
      for(int e=1;e<4;e++) if (ev[e] > lv){ lv=ev[e]; le=e; }
      float gv = lv; int gk = j*4 + le;
      #pragma unroll
      for(int o=8;o>0;o>>=1){
        float ov = __shfl_xor(gv,o,64); int ok = __shfl_xor(gk,o,64);
        if (ov > gv || (ov == gv && ok < gk)){ gv=ov; gk=ok; }
      }
      const int estar = gk&3, h = gk>>2;
      int seli = posj[0];
      seli = (estar==1) ? posj[1] : seli;
      seli = (estar==2) ? posj[2] : seli;
      seli = (estar==3) ? posj[3] : seli;
      const int wpos = __shfl(seli, (lane & 48) | h, 64);
      #pragma unroll
      for(int e=0;e<4;e++) if (j==h && e==estar) ev[e] = -1e30f;
      if (j == r) cap = wpos;
    }
    if (j < 8){
      const int sp = (2*gy + (g>>1))*64 + 2*gx + (g&1);
      topk1[((size_t)bh*4096 + sp)*8 + j] = cap;
    }
  }

  // ---- msg1 = A @ gathered V: lane = (t,dd) ----
  {
    const int t = lane>>4, dd = lane&15;
    float a = 0.f;
    #pragma unroll
    for(int kk=0;kk<64;kk++) a = fmaf(s_e[wid][t][kk], s_v[wid][dd][kk], a);
    const int sp = (2*gy + (t>>1))*64 + 2*gx + (t&1);
    msg1[((size_t)bh*4096 + sp)*16 + dd] = a;
  }
}

// ---------------- fine: K=32 gathered children + fused combine --------------
template<bool TOK>
__global__ __launch_bounds__(256) void k_fine(
    const float* __restrict__ q, const float* __restrict__ k, const float* __restrict__ v,
    const float* __restrict__ ktok, const float* __restrict__ vtok,
    const int* __restrict__ topk1, const float* __restrict__ msg0,
    const float* __restrict__ msg1, const float* __restrict__ wvec,
    float* __restrict__ out)
{
  __shared__ float s_k[4][16][34];
  __shared__ float s_v[4][16][34];
  __shared__ float s_q[4][4][17];
  __shared__ float s_e[4][4][33];
  const int tid = threadIdx.x, wid = tid>>6, lane = tid&63;
  const int slot = __builtin_amdgcn_readfirstlane(blockIdx.x*4 + wid);
  const int l = slot & 4095, bh = slot >> 12;
  const int b = bh>>3, h = bh&7;
  const int gy = l>>6, gx = l&63;

  const float* qb = q + (size_t)bh*262144;

  {
    const int t = lane>>4, dd = lane&15;
    const int qp = (2*gy + (t>>1))*128 + 2*gx + (t&1);
    s_q[wid][t][dd] = qb[dd*16384 + qp];
  }
  if constexpr (TOK){
    const int key = lane&31, half = lane>>5;
    const int w = key>>2, c = key&3;
    const int widx = topk1[(size_t)slot*8 + w];
    const int pos = (2*(widx>>6) + (c>>1))*128 + 2*(widx&63) + (c&1);
    const float4* sp4 = (const float4*)((half ? vtok : ktok) + ((size_t)bh*16384 + pos)*16);
    float4 x0=sp4[0], x1=sp4[1], x2=sp4[2], x3=sp4[3];
    float* dst = (half ? &s_v[wid][0][0] : &s_k[wid][0][0]);
    dst[0*34+key]=x0.x;  dst[1*34+key]=x0.y;  dst[2*34+key]=x0.z;  dst[3*34+key]=x0.w;
    dst[4*34+key]=x1.x;  dst[5*34+key]=x1.y;  dst[6*34+key]=x1.z;  dst[7*34+key]=x1.w;
    dst[8*34+key]=x2.x;  dst[9*34+key]=x2.y;  dst[10*34+key]=x2.z; dst[11*34+key]=x2.w;
    dst[12*34+key]=x3.x; dst[13*34+key]=x3.y; dst[14*34+key]=x3.z; dst[15*34+key]=x3.w;
  } else {
    const int gs = lane>>1, dh = lane&1;
    const int kvsel = gs>>4, rr = gs&15, w = rr>>1, cy = rr&1;
    const int widx = topk1[(size_t)slot*8 + w];
    const int base = (2*(widx>>6) + cy)*128 + 2*(widx&63);
    const float* src = (kvsel ? v : k) + (size_t)bh*262144;
    float* dst = kvsel ? &s_v[wid][0][0] : &s_k[wid][0][0];
    const int key0 = w*4 + cy*2;
    #pragma unroll
    for(int jj=0;jj<8;jj++){
      const int dd = dh*8 + jj;
      const float2 f2 = *(const float2*)(src + dd*16384 + base);
      *(float2*)(dst + dd*34 + key0) = f2;
    }
  }

  const int key = lane&31, th = lane>>5;
  float kv[16];
  #pragma unroll
  for(int dd=0;dd<16;dd++) kv[dd] = s_k[wid][dd][key];
  #pragma unroll
  for(int tt=0;tt<2;tt++){
    const int t = th*2 + tt;
    float a = 0.f;
    #pragma unroll
    for(int dd=0;dd<16;dd++) a = fmaf(s_q[wid][t][dd], kv[dd], a);
    a *= 0.25f;
    const float m = half_max(a);
    const float e = __expf(a - m);
    const float s = half_sum(e);
    s_e[wid][t][key] = e / s;
  }

  const float w0i = wvec[0], w1i = wvec[1], w2i = wvec[2];
  const float wm = fmaxf(w0i, fmaxf(w1i, w2i));
  float e0 = __expf(w0i-wm), e1 = __expf(w1i-wm), e2 = __expf(w2i-wm);
  const float wsum = e0+e1+e2;
  e0/=wsum; e1/=wsum; e2/=wsum;

  const int t2 = lane>>4, dd2 = lane&15;
  float a = 0.f;
  #pragma unroll
  for(int kk=0;kk<32;kk++) a = fmaf(s_e[wid][t2][kk], s_v[wid][dd2][kk], a);

  const int cl = (gy>>1)*32 + (gx>>1);
  const float m0 = msg0[((size_t)bh*1024 + cl)*16 + dd2];
  const float m1 = msg1[(size_t)slot*16 + dd2];
  const int pp = (2*gy + (t2>>1))*128 + 2*gx + (t2&1);
  out[(((size_t)b*16384 + pp)*8 + h)*16 + dd2] = e0*m0 + e1*m1 + e2*a;
}

extern "C" void kernel_launch(void* const* d_in, const int* in_sizes, int n_in,
                              void* d_out, int out_size, void* d_ws, size_t ws_size,
                              hipStream_t stream) {
  const float* q0 = (const float*)d_in[0];
  const float* q1 = (const float*)d_in[1];
  const float* q2 = (const float*)d_in[2];
  const float* k0 = (const float*)d_in[3];
  const float* k1 = (const float*)d_in[4];
  const float* k2 = (const float*)d_in[5];
  const float* v0 = (const float*)d_in[6];
  const float* v1 = (const float*)d_in[7];
  const float* v2 = (const float*)d_in[8];
  const float* wv = (const float*)d_in[9];
  float* out = (float*)d_out;

  float* msg0  = (float*)d_ws;                 // 524288 f
  int*   topk0 = (int*)(msg0 + 524288);        // 524288 i
  float* msg1  = (float*)(topk0 + 524288);     // 2097152 f
  int*   topk1 = (int*)(msg1 + 2097152);       // 1048576 i
  float* ktok0 = (float*)(topk1 + 1048576);    // 8388608 f
  float* vtok0 = ktok0 + 8388608;              // 8388608 f
  float* ktok1 = vtok0 + 8388608;              // 2097152 f
  float* vtok1 = ktok1 + 2097152;              // 2097152 f
  float* ktok2 = vtok1 + 2097152;              // 524288 f
  float* vtok2 = ktok2 + 524288;               // 524288 f

  const size_t needA = (size_t)(4194304 + 22020096) * 4;  // 104,857,600 B

  if (ws_size >= needA){
    hipLaunchKernelGGL(k_pre,  dim3(256),  dim3(256), 0, stream, k2, v2, ktok2, vtok2);
    hipLaunchKernelGGL(k_mega, dim3(9216), dim3(256), 0, stream,
                       q2,k2,v2, ktok2,vtok2, msg0, topk0,
                       k0,v0,k1,v1, ktok0,vtok0,ktok1,vtok1);
    hipLaunchKernelGGL(k_mid<true>,  dim3(8192),  dim3(256), 0, stream,
                       q1,k1,v1, ktok1,vtok1, topk0, msg1, topk1);
    hipLaunchKernelGGL(k_fine<true>, dim3(32768), dim3(256), 0, stream,
                       q0,k0,v0, ktok0,vtok0, topk1, msg0, msg1, wv, out);
  } else {
    hipLaunchKernelGGL(k_coarse_fb,   dim3(4096),  dim3(256), 0, stream, q2,k2,v2, msg0, topk0);
    hipLaunchKernelGGL(k_mid<false>,  dim3(8192),  dim3(256), 0, stream,
                       q1,k1,v1, (float*)d_ws,(float*)d_ws, topk0, msg1, topk1);
    hipLaunchKernelGGL(k_fine<false>, dim3(32768), dim3(256), 0, stream,
                       q0,k0,v0, (float*)d_ws,(float*)d_ws, topk1, msg0, msg1, wv, out);
  }
}

// Round 8
// 461.402 us; speedup vs baseline: 1.2710x; 1.2710x over previous
//
#include <hip/hip_runtime.h>

// Quadtree attention forward, 3 levels. B=4, C=128, nh=8, d=16, topks=(16,8,8).
// Round 8: coarse+mid fused per-wave (caps via __shfl, no topk0 global);
// homogeneous transpose kernels (small pre before fused, k0/v0 after);
// R7 coarse body (folded reductions, deferred norm); fine = R5 form.

#define DEV static __device__ __forceinline__

DEV float wave_max(float v){
  #pragma unroll
  for(int o=32;o>0;o>>=1) v = fmaxf(v, __shfl_xor(v,o,64));
  return v;
}
DEV float wave_sum(float v){
  #pragma unroll
  for(int o=32;o>0;o>>=1) v += __shfl_xor(v,o,64);
  return v;
}
DEV float half_max(float v){
  #pragma unroll
  for(int o=16;o>0;o>>=1) v = fmaxf(v, __shfl_xor(v,o,64));
  return v;
}
DEV float half_sum(float v){
  #pragma unroll
  for(int o=16;o>0;o>>=1) v += __shfl_xor(v,o,64);
  return v;
}

// masked local top-4 scan (ascending c, strict > => tie keeps lowest c)
DEV void scan4(const float (&sc)[16], unsigned &rem, float (&tv)[4], int (&tc)[4]){
  #pragma unroll
  for(int t=0;t<4;t++){
    float bv=-1e30f; int bc=0;
    #pragma unroll
    for(int c=0;c<16;c++){
      const bool ok = (((rem>>c)&1u)==0u) && (sc[c] > bv);
      bv = ok ? sc[c] : bv;
      bc = ok ? c : bc;
    }
    tv[t]=bv; tc[t]=bc; rem |= (1u<<bc);
  }
}

// top-16 for two queries, interleaved rounds; lane holds sc[c] for s=c*64+lane.
// ties -> lowest s. Non-destructive on sc. Rank r lands on lane r.
DEV void top16_pair(const float (&sc0)[16], const float (&sc1)[16], int lane,
                    int &cap0, int &cap1){
  unsigned rem0=0u, rem1=0u;
  float tv0[4], tv1[4]; int tc0[4], tc1[4];
  scan4(sc0, rem0, tv0, tc0);
  scan4(sc1, rem1, tv1, tc1);
  cap0=0; cap1=0;
  #pragma unroll 1
  for(int r=0;r<16;r++){
    const float M0 = wave_max(tv0[0]);
    const float M1 = wave_max(tv1[0]);
    const unsigned long long k0 = __ballot(tv0[0]==M0);
    const unsigned long long k1 = __ballot(tv1[0]==M1);
    int wl0 = (int)__ffsll(k0)-1, ws0;
    int wl1 = (int)__ffsll(k1)-1, ws1;
    if (__popcll(k0)==1){ ws0 = __shfl(tc0[0], wl0)*64 + wl0; }
    else {
      int sel = (tv0[0]==M0) ? (tc0[0]*64+lane) : 0x7fffffff;
      #pragma unroll
      for(int o=32;o>0;o>>=1) sel = min(sel, __shfl_xor(sel,o,64));
      ws0 = sel; wl0 = ws0 & 63;
    }
    if (__popcll(k1)==1){ ws1 = __shfl(tc1[0], wl1)*64 + wl1; }
    else {
      int sel = (tv1[0]==M1) ? (tc1[0]*64+lane) : 0x7fffffff;
      #pragma unroll
      for(int o=32;o>0;o>>=1) sel = min(sel, __shfl_xor(sel,o,64));
      ws1 = sel; wl1 = ws1 & 63;
    }
    cap0 = (lane==r) ? ws0 : cap0;
    cap1 = (lane==r) ? ws1 : cap1;
    if (lane==wl0){
      tv0[0]=tv0[1]; tc0[0]=tc0[1];
      tv0[1]=tv0[2]; tc0[1]=tc0[2];
      tv0[2]=tv0[3]; tc0[2]=tc0[3];
      tv0[3]=-1e30f; tc0[3]=0;
      if (tv0[0] < -1e29f) scan4(sc0, rem0, tv0, tc0);
    }
    if (lane==wl1){
      tv1[0]=tv1[1]; tc1[0]=tc1[1];
      tv1[1]=tv1[2]; tc1[1]=tc1[2];
      tv1[2]=tv1[3]; tc1[2]=tc1[3];
      tv1[3]=-1e30f; tc1[3]=0;
      if (tv1[0] < -1e29f) scan4(sc1, rem1, tv1, tc1);
    }
  }
}

// fold 16 accumulators over 64 lanes -> partial for dd=lane&15 (15 shfl).
DEV float fold16(float (&a)[16], int lane){
  #pragma unroll
  for(int st=0; st<4; st++){
    const int o = 1<<st, nh = 8>>st;
    const int b = (lane>>st)&1;
    #pragma unroll
    for(int i=0;i<nh;i++){
      const float x = a[2*i], y = a[2*i+1];
      const float send = b ? x : y;
      const float keep = b ? y : x;
      a[i] = keep + __shfl_xor(send, o, 64);
    }
  }
  return a[0];
}

// ---------------- coarse core (2 queries/wave, no LDS/barriers) ------------
// Returns cap0/cap1 (rank r on lane r); writes msg0; optional topk0 store.
template<bool TOK, bool STORETK>
DEV void coarse_core(int cid, int tid,
    const float* __restrict__ q, const float* __restrict__ k, const float* __restrict__ v,
    const float* __restrict__ ktok, const float* __restrict__ vtok,
    float* __restrict__ msg0, int* __restrict__ topk0, int &cap0, int &cap1)
{
  const int wid = tid>>6, lane = tid&63;
  const int gq0 = __builtin_amdgcn_readfirstlane((cid*4 + wid)*2);
  const int bh = gq0>>10, l0 = gq0&1023;

  const float* qb = q + (size_t)bh*16384;
  float qv0[16], qv1[16];
  #pragma unroll
  for(int dd=0;dd<16;dd++){ qv0[dd]=qb[dd*1024+l0]*0.25f; qv1[dd]=qb[dd*1024+l0+1]*0.25f; }

  // ---- pass 1: scores (s = c*64 + lane) ----
  float sc0[16], sc1[16];
  #pragma unroll
  for(int c=0;c<16;c++){
    const int s = c*64 + lane;
    float kr[16];
    if constexpr (TOK){
      const float4* kp = (const float4*)(ktok + ((size_t)bh*1024 + s)*16);
      float4 x0=kp[0], x1=kp[1], x2=kp[2], x3=kp[3];
      kr[0]=x0.x; kr[1]=x0.y; kr[2]=x0.z; kr[3]=x0.w;
      kr[4]=x1.x; kr[5]=x1.y; kr[6]=x1.z; kr[7]=x1.w;
      kr[8]=x2.x; kr[9]=x2.y; kr[10]=x2.z; kr[11]=x2.w;
      kr[12]=x3.x; kr[13]=x3.y; kr[14]=x3.z; kr[15]=x3.w;
    } else {
      const float* kb = k + (size_t)bh*16384 + s;
      #pragma unroll
      for(int dd=0;dd<16;dd++) kr[dd] = kb[dd*1024];
    }
    float a0=0.f, a1=0.f;
    #pragma unroll
    for(int dd=0;dd<16;dd++){ a0=fmaf(qv0[dd],kr[dd],a0); a1=fmaf(qv1[dd],kr[dd],a1); }
    sc0[c]=a0; sc1[c]=a1;
  }

  // ---- top-16 on raw scores ----
  top16_pair(sc0, sc1, lane, cap0, cap1);
  if (STORETK && lane < 16){
    topk0[(size_t)gq0*16 + lane]     = cap0;
    topk0[(size_t)(gq0+1)*16 + lane] = cap1;
  }

  // ---- folded max over both queries ----
  float m0l=-1e30f, m1l=-1e30f;
  #pragma unroll
  for(int c=0;c<16;c++){ m0l=fmaxf(m0l,sc0[c]); m1l=fmaxf(m1l,sc1[c]); }
  float m0, m1;
  {
    float t  = (lane&16) ? m1l : m0l;
    float sd = (lane&16) ? m0l : m1l;
    t = fmaxf(t, __shfl_xor(sd,16,64));
    t = fmaxf(t, __shfl_xor(t,32,64));
    t = fmaxf(t, __shfl_xor(t, 8,64));
    t = fmaxf(t, __shfl_xor(t, 4,64));
    t = fmaxf(t, __shfl_xor(t, 2,64));
    t = fmaxf(t, __shfl_xor(t, 1,64));
    const float to = __shfl_xor(t,16,64);
    m0 = (lane&16) ? to : t;
    m1 = (lane&16) ? t  : to;
  }

  float s0l=0.f, s1l=0.f;
  #pragma unroll
  for(int c=0;c<16;c++){
    sc0[c]=__expf(sc0[c]-m0); s0l+=sc0[c];
    sc1[c]=__expf(sc1[c]-m1); s1l+=sc1[c];
  }
  float inv;
  {
    float t  = (lane&16) ? s1l : s0l;
    float sd = (lane&16) ? s0l : s1l;
    t += __shfl_xor(sd,16,64);
    t += __shfl_xor(t,32,64);
    t += __shfl_xor(t, 8,64);
    t += __shfl_xor(t, 4,64);
    t += __shfl_xor(t, 2,64);
    t += __shfl_xor(t, 1,64);
    inv = 1.0f / t;
  }

  // ---- pass 2: AV ----
  float acc0[16], acc1[16];
  #pragma unroll
  for(int dd=0;dd<16;dd++){ acc0[dd]=0.f; acc1[dd]=0.f; }
  #pragma unroll
  for(int c=0;c<16;c++){
    const int s = c*64 + lane;
    float vr[16];
    if constexpr (TOK){
      const float4* vp = (const float4*)(vtok + ((size_t)bh*1024 + s)*16);
      float4 x0=vp[0], x1=vp[1], x2=vp[2], x3=vp[3];
      vr[0]=x0.x; vr[1]=x0.y; vr[2]=x0.z; vr[3]=x0.w;
      vr[4]=x1.x; vr[5]=x1.y; vr[6]=x1.z; vr[7]=x1.w;
      vr[8]=x2.x; vr[9]=x2.y; vr[10]=x2.z; vr[11]=x2.w;
      vr[12]=x3.x; vr[13]=x3.y; vr[14]=x3.z; vr[15]=x3.w;
    } else {
      const float* vb = v + (size_t)bh*16384 + s;
      #pragma unroll
      for(int dd=0;dd<16;dd++) vr[dd] = vb[dd*1024];
    }
    const float p0c = sc0[c], p1c = sc1[c];
    #pragma unroll
    for(int dd=0;dd<16;dd++){ acc0[dd]=fmaf(p0c,vr[dd],acc0[dd]); acc1[dd]=fmaf(p1c,vr[dd],acc1[dd]); }
  }
  const float a0f = fold16(acc0, lane);
  const float a1f = fold16(acc1, lane);
  {
    const float mine = (lane&16) ? a1f : a0f;
    const float send = (lane&16) ? a0f : a1f;
    float tot = mine + __shfl_xor(send,16,64);
    tot += __shfl_xor(tot,32,64);
    tot *= inv;
    if (lane < 32) msg0[(size_t)(gq0 + (lane>>4))*16 + (lane&15)] = tot;
  }
}

// ---------------- mid group body (TOK, wave-private LDS, cap in regs) -------
DEV void mid_group(int lane, int bh, int l, int cap,
    const float* __restrict__ qb, const float* __restrict__ ktokb,
    const float* __restrict__ vtokb,
    float* __restrict__ svw /*[16][66]*/, float* __restrict__ sew /*[4][65]*/,
    float* __restrict__ msg1, int* __restrict__ topk1)
{
  const int gy = l>>5, gx = l&31;
  const int widx = __shfl(cap, lane>>2, 64);
  const int c = lane&3;
  const int pos = (2*(widx>>5) + (c>>1))*64 + 2*(widx&31) + (c&1);

  float kv[16];
  {
    const float4* kp = (const float4*)(ktokb + (size_t)pos*16);
    float4 x0=kp[0], x1=kp[1], x2=kp[2], x3=kp[3];
    kv[0]=x0.x; kv[1]=x0.y; kv[2]=x0.z; kv[3]=x0.w;
    kv[4]=x1.x; kv[5]=x1.y; kv[6]=x1.z; kv[7]=x1.w;
    kv[8]=x2.x; kv[9]=x2.y; kv[10]=x2.z; kv[11]=x2.w;
    kv[12]=x3.x; kv[13]=x3.y; kv[14]=x3.z; kv[15]=x3.w;
    const float4* vp = (const float4*)(vtokb + (size_t)pos*16);
    float4 y0=vp[0], y1=vp[1], y2=vp[2], y3=vp[3];
    svw[0*66+lane]=y0.x;  svw[1*66+lane]=y0.y;  svw[2*66+lane]=y0.z;  svw[3*66+lane]=y0.w;
    svw[4*66+lane]=y1.x;  svw[5*66+lane]=y1.y;  svw[6*66+lane]=y1.z;  svw[7*66+lane]=y1.w;
    svw[8*66+lane]=y2.x;  svw[9*66+lane]=y2.y;  svw[10*66+lane]=y2.z; svw[11*66+lane]=y2.w;
    svw[12*66+lane]=y3.x; svw[13*66+lane]=y3.y; svw[14*66+lane]=y3.z; svw[15*66+lane]=y3.w;
  }

  // ---- scores + softmax (lane = gathered key) ----
  #pragma unroll
  for(int t=0;t<4;t++){
    const int qp = (2*gy + (t>>1))*64 + 2*gx + (t&1);
    float a = 0.f;
    #pragma unroll
    for(int dd=0;dd<16;dd++) a = fmaf(qb[dd*4096 + qp], kv[dd], a);
    a *= 0.25f;
    const float m = wave_max(a);
    const float e = __expf(a - m);
    const float s = wave_sum(e);
    sew[t*65 + lane] = e / s;
  }

  // ---- top-8: group g (16 lanes) handles t=g; lane j owns keys j*4+e ----
  const int g = lane>>4, j = lane&15;
  {
    const int wj_ = __shfl(cap, j, 64);
    const int tyj = wj_>>5, txj = wj_&31;
    int posj[4];
    #pragma unroll
    for(int e=0;e<4;e++) posj[e] = (2*tyj + (e>>1))*64 + 2*txj + (e&1);
    float ev[4];
    #pragma unroll
    for(int e=0;e<4;e++) ev[e] = sew[g*65 + j*4+e];
    int capk = 0;
    for(int r=0;r<8;r++){
      float lv = ev[0]; int le = 0;
      #pragma unroll
      for(int e=1;e<4;e++) if (ev[e] > lv){ lv=ev[e]; le=e; }
      float gv = lv; int gk = j*4 + le;
      #pragma unroll
      for(int o=8;o>0;o>>=1){
        float ov = __shfl_xor(gv,o,64); int ok = __shfl_xor(gk,o,64);
        if (ov > gv || (ov == gv && ok < gk)){ gv=ov; gk=ok; }
      }
      const int estar = gk&3, hwin = gk>>2;
      int seli = posj[0];
      seli = (estar==1) ? posj[1] : seli;
      seli = (estar==2) ? posj[2] : seli;
      seli = (estar==3) ? posj[3] : seli;
      const int wpos = __shfl(seli, (lane & 48) | hwin, 64);
      #pragma unroll
      for(int e=0;e<4;e++) if (j==hwin && e==estar) ev[e] = -1e30f;
      if (j == r) capk = wpos;
    }
    if (j < 8){
      const int sp = (2*gy + (g>>1))*64 + 2*gx + (g&1);
      topk1[((size_t)bh*4096 + sp)*8 + j] = capk;
    }
  }

  // ---- msg1 = A @ gathered V: lane = (t,dd) ----
  {
    const int t = lane>>4, dd = lane&15;
    float a = 0.f;
    #pragma unroll
    for(int kk=0;kk<64;kk++) a = fmaf(sew[t*65 + kk], svw[dd*66 + kk], a);
    const int sp = (2*gy + (t>>1))*64 + 2*gx + (t&1);
    msg1[((size_t)bh*4096 + sp)*16 + dd] = a;
  }
}

// ---------------- fused coarse+mid ------------------------------------------
__global__ __launch_bounds__(256) void k_cm(
    const float* __restrict__ q2, const float* __restrict__ k2, const float* __restrict__ v2,
    const float* __restrict__ ktok2, const float* __restrict__ vtok2,
    const float* __restrict__ q1,
    const float* __restrict__ ktok1, const float* __restrict__ vtok1,
    float* __restrict__ msg0, float* __restrict__ msg1, int* __restrict__ topk1)
{
  __shared__ float s_v[4][16][66];
  __shared__ float s_e[4][4][65];
  const int tid = threadIdx.x, wid = tid>>6, lane = tid&63;

  int cap0, cap1;
  coarse_core<true,false>(blockIdx.x, tid, q2,k2,v2, ktok2,vtok2,
                          msg0, nullptr, cap0, cap1);

  const int gq0 = __builtin_amdgcn_readfirstlane((blockIdx.x*4 + wid)*2);
  const int bh = gq0>>10, l0 = gq0&1023;
  const float* qb1   = q1 + (size_t)bh*65536;
  const float* ktokb = ktok1 + (size_t)bh*4096*16;
  const float* vtokb = vtok1 + (size_t)bh*4096*16;
  float* svw = &s_v[wid][0][0];
  float* sew = &s_e[wid][0][0];

  mid_group(lane, bh, l0,   cap0, qb1, ktokb, vtokb, svw, sew, msg1, topk1);
  mid_group(lane, bh, l0+1, cap1, qb1, ktokb, vtokb, svw, sew, msg1, topk1);
}

// ---------------- transpose helpers -----------------------------------------
DEV void transpose_body(const float* __restrict__ src, float* __restrict__ dst,
                        int id, int lgS)
{
  const int s = id & ((1<<lgS)-1), bh = id >> lgS;
  const float* sp = src + ((size_t)bh<<(lgS+4)) + s;
  float r[16];
  #pragma unroll
  for(int dd=0;dd<16;dd++) r[dd] = sp[(size_t)dd<<lgS];
  float4* dp = (float4*)(dst + (size_t)id*16);
  dp[0] = make_float4(r[0],r[1],r[2],r[3]);
  dp[1] = make_float4(r[4],r[5],r[6],r[7]);
  dp[2] = make_float4(r[8],r[9],r[10],r[11]);
  dp[3] = make_float4(r[12],r[13],r[14],r[15]);
}

// pre: k1,v1,k2,v2 -> token-major (1280 blocks)
__global__ __launch_bounds__(256) void k_pre2(
    const float* __restrict__ k1, const float* __restrict__ v1,
    const float* __restrict__ k2, const float* __restrict__ v2,
    float* __restrict__ ktok1, float* __restrict__ vtok1,
    float* __restrict__ ktok2, float* __restrict__ vtok2)
{
  const int blk = blockIdx.x;
  const float* src; float* dst; int lgS, base;
  if      (blk < 512){  lgS=12; src=k1; dst=ktok1; base=0; }
  else if (blk < 1024){ lgS=12; src=v1; dst=vtok1; base=512; }
  else if (blk < 1152){ lgS=10; src=k2; dst=ktok2; base=1024; }
  else                { lgS=10; src=v2; dst=vtok2; base=1152; }
  transpose_body(src, dst, (blk-base)*256 + threadIdx.x, lgS);
}

// tr0: k0,v0 -> token-major (4096 blocks)
__global__ __launch_bounds__(256) void k_tr0(
    const float* __restrict__ k0, const float* __restrict__ v0,
    float* __restrict__ ktok0, float* __restrict__ vtok0)
{
  const int blk = blockIdx.x;
  const float* src = (blk < 2048) ? k0 : v0;
  float* dst = (blk < 2048) ? ktok0 : vtok0;
  transpose_body(src, dst, (blk & 2047)*256 + threadIdx.x, 14);
}

// ---------------- fallback kernels (small ws) -------------------------------
__global__ __launch_bounds__(256) void k_coarse_fb(
    const float* __restrict__ q, const float* __restrict__ k, const float* __restrict__ v,
    float* __restrict__ msg0, int* __restrict__ topk0)
{
  int c0, c1;
  coarse_core<false,true>(blockIdx.x, threadIdx.x, q,k,v, nullptr,nullptr, msg0, topk0, c0, c1);
}

__global__ __launch_bounds__(256) void k_mid_fb(
    const float* __restrict__ q, const float* __restrict__ k, const float* __restrict__ v,
    const int* __restrict__ topk0, float* __restrict__ msg1, int* __restrict__ topk1)
{
  __shared__ float s_v[4][16][66];
  __shared__ float s_e[4][4][65];
  __shared__ float s_k[4][16][66];
  const int tid = threadIdx.x, wid = tid>>6, lane = tid&63;
  const int slot = __builtin_amdgcn_readfirstlane(blockIdx.x*4 + wid);
  const int l = slot & 1023, bh = slot >> 10;
  const int gy = l>>5, gx = l&31;
  const float* qb = q + (size_t)bh*65536;

  {
    const int kvsel = lane>>5, rr = lane&31, w = rr>>1, cy = rr&1;
    const int widx = topk0[(size_t)slot*16 + w];
    const int base = (2*(widx>>5) + cy)*64 + 2*(widx&31);
    const float* src = (kvsel ? v : k) + (size_t)bh*65536;
    float* dst = kvsel ? &s_v[wid][0][0] : &s_k[wid][0][0];
    const int key0 = w*4 + cy*2;
    #pragma unroll
    for(int dd=0;dd<16;dd++){
      const float2 f2 = *(const float2*)(src + dd*4096 + base);
      *(float2*)(dst + dd*66 + key0) = f2;
    }
  }
  float kv[16];
  #pragma unroll
  for(int dd=0;dd<16;dd++) kv[dd] = s_k[wid][dd][lane];

  #pragma unroll
  for(int t=0;t<4;t++){
    const int qp = (2*gy + (t>>1))*64 + 2*gx + (t&1);
    float a = 0.f;
    #pragma unroll
    for(int dd=0;dd<16;dd++) a = fmaf(qb[dd*4096 + qp], kv[dd], a);
    a *= 0.25f;
    const float m = wave_max(a);
    const float e = __expf(a - m);
    const float s = wave_sum(e);
    s_e[wid][t][lane] = e / s;
  }

  const int g = lane>>4, j = lane&15;
  {
    const int wj_ = topk0[(size_t)slot*16 + j];
    const int tyj = wj_>>5, txj = wj_&31;
    int posj[4];
    #pragma unroll
    for(int e=0;e<4;e++) posj[e] = (2*tyj + (e>>1))*64 + 2*txj + (e&1);
    float ev[4];
    #pragma unroll
    for(int e=0;e<4;e++) ev[e] = s_e[wid][g][j*4+e];
    int cap = 0;
    for(int r=0;r<8;r++){
      float lv = ev[0]; int le = 0;
      #pragma unroll
      for(int e=1;e<4;e++) if (ev[e] > lv){ lv=ev[e]; le=e; }
      float gv = lv; int gk = j*4 + le;
      #pragma unroll
      for(int o=8;o>0;o>>=1){
        float ov = __shfl_xor(gv,o,64); int ok = __shfl_xor(gk,o,64);
        if (ov > gv || (ov == gv && ok < gk)){ gv=ov; gk=ok; }
      }
      const int estar = gk&3, hwin = gk>>2;
      int seli = posj[0];
      seli = (estar==1) ? posj[1] : seli;
      seli = (estar==2) ? posj[2] : seli;
      seli = (estar==3) ? posj[3] : seli;
      const int wpos = __shfl(seli, (lane & 48) | hwin, 64);
      #pragma unroll
      for(int e=0;e<4;e++) if (j==hwin && e==estar) ev[e] = -1e30f;
      if (j == r) cap = wpos;
    }
    if (j < 8){
      const int sp = (2*gy + (g>>1))*64 + 2*gx + (g&1);
      topk1[((size_t)bh*4096 + sp)*8 + j] = cap;
    }
  }
  {
    const int t = lane>>4, dd = lane&15;
    float a = 0.f;
    #pragma unroll
    for(int kk=0;kk<64;kk++) a = fmaf(s_e[wid][t][kk], s_v[wid][dd][kk], a);
    const int sp = (2*gy + (t>>1))*64 + 2*gx + (t&1);
    msg1[((size_t)bh*4096 + sp)*16 + dd] = a;
  }
}

// ---------------- fine: K=32 gathered children + fused combine --------------
template<bool TOK>
__global__ __launch_bounds__(256) void k_fine(
    const float* __restrict__ q, const float* __restrict__ k, const float* __restrict__ v,
    const float* __restrict__ ktok, const float* __restrict__ vtok,
    const int* __restrict__ topk1, const float* __restrict__ msg0,
    const float* __restrict__ msg1, const float* __restrict__ wvec,
    float* __restrict__ out)
{
  __shared__ float s_k[4][16][34];
  __shared__ float s_v[4][16][34];
  __shared__ float s_q[4][4][17];
  __shared__ float s_e[4][4][33];
  const int tid = threadIdx.x, wid = tid>>6, lane = tid&63;
  const int slot = __builtin_amdgcn_readfirstlane(blockIdx.x*4 + wid);
  const int l = slot & 4095, bh = slot >> 12;
  const int b = bh>>3, h = bh&7;
  const int gy = l>>6, gx = l&63;

  const float* qb = q + (size_t)bh*262144;

  {
    const int t = lane>>4, dd = lane&15;
    const int qp = (2*gy + (t>>1))*128 + 2*gx + (t&1);
    s_q[wid][t][dd] = qb[dd*16384 + qp];
  }
  if constexpr (TOK){
    const int key = lane&31, half = lane>>5;
    const int w = key>>2, c = key&3;
    const int widx = topk1[(size_t)slot*8 + w];
    const int pos = (2*(widx>>6) + (c>>1))*128 + 2*(widx&63) + (c&1);
    const float4* sp4 = (const float4*)((half ? vtok : ktok) + ((size_t)bh*16384 + pos)*16);
    float4 x0=sp4[0], x1=sp4[1], x2=sp4[2], x3=sp4[3];
    float* dst = (half ? &s_v[wid][0][0] : &s_k[wid][0][0]);
    dst[0*34+key]=x0.x;  dst[1*34+key]=x0.y;  dst[2*34+key]=x0.z;  dst[3*34+key]=x0.w;
    dst[4*34+key]=x1.x;  dst[5*34+key]=x1.y;  dst[6*34+key]=x1.z;  dst[7*34+key]=x1.w;
    dst[8*34+key]=x2.x;  dst[9*34+key]=x2.y;  dst[10*34+key]=x2.z; dst[11*34+key]=x2.w;
    dst[12*34+key]=x3.x; dst[13*34+key]=x3.y; dst[14*34+key]=x3.z; dst[15*34+key]=x3.w;
  } else {
    const int gs = lane>>1, dh = lane&1;
    const int kvsel = gs>>4, rr = gs&15, w = rr>>1, cy = rr&1;
    const int widx = topk1[(size_t)slot*8 + w];
    const int base = (2*(widx>>6) + cy)*128 + 2*(widx&63);
    const float* src = (kvsel ? v : k) + (size_t)bh*262144;
    float* dst = kvsel ? &s_v[wid][0][0] : &s_k[wid][0][0];
    const int key0 = w*4 + cy*2;
    #pragma unroll
    for(int jj=0;jj<8;jj++){
      const int dd = dh*8 + jj;
      const float2 f2 = *(const float2*)(src + dd*16384 + base);
      *(float2*)(dst + dd*34 + key0) = f2;
    }
  }

  const int key = lane&31, th = lane>>5;
  float kv[16];
  #pragma unroll
  for(int dd=0;dd<16;dd++) kv[dd] = s_k[wid][dd][key];
  #pragma unroll
  for(int tt=0;tt<2;tt++){
    const int t = th*2 + tt;
    float a = 0.f;
    #pragma unroll
    for(int dd=0;dd<16;dd++) a = fmaf(s_q[wid][t][dd], kv[dd], a);
    a *= 0.25f;
    const float m = half_max(a);
    const float e = __expf(a - m);
    const float s = half_sum(e);
    s_e[wid][t][key] = e / s;
  }

  const float w0i = wvec[0], w1i = wvec[1], w2i = wvec[2];
  const float wm = fmaxf(w0i, fmaxf(w1i, w2i));
  float e0 = __expf(w0i-wm), e1 = __expf(w1i-wm), e2 = __expf(w2i-wm);
  const float wsum = e0+e1+e2;
  e0/=wsum; e1/=wsum; e2/=wsum;

  const int t2 = lane>>4, dd2 = lane&15;
  float a = 0.f;
  #pragma unroll
  for(int kk=0;kk<32;kk++) a = fmaf(s_e[wid][t2][kk], s_v[wid][dd2][kk], a);

  const int cl = (gy>>1)*32 + (gx>>1);
  const float m0 = msg0[((size_t)bh*1024 + cl)*16 + dd2];
  const float m1 = msg1[(size_t)slot*16 + dd2];
  const int pp = (2*gy + (t2>>1))*128 + 2*gx + (t2&1);
  out[(((size_t)b*16384 + pp)*8 + h)*16 + dd2] = e0*m0 + e1*m1 + e2*a;
}

extern "C" void kernel_launch(void* const* d_in, const int* in_sizes, int n_in,
                              void* d_out, int out_size, void* d_ws, size_t ws_size,
                              hipStream_t stream) {
  const float* q0 = (const float*)d_in[0];
  const float* q1 = (const float*)d_in[1];
  const float* q2 = (const float*)d_in[2];
  const float* k0 = (const float*)d_in[3];
  const float* k1 = (const float*)d_in[4];
  const float* k2 = (const float*)d_in[5];
  const float* v0 = (const float*)d_in[6];
  const float* v1 = (const float*)d_in[7];
  const float* v2 = (const float*)d_in[8];
  const float* wv = (const float*)d_in[9];
  float* out = (float*)d_out;

  float* msg0  = (float*)d_ws;                 // 524288 f
  int*   topk0 = (int*)(msg0 + 524288);        // 524288 i (fallback only)
  float* msg1  = (float*)(topk0 + 524288);     // 2097152 f
  int*   topk1 = (int*)(msg1 + 2097152);       // 1048576 i
  float* ktok0 = (float*)(topk1 + 1048576);    // 8388608 f
  float* vtok0 = ktok0 + 8388608;              // 8388608 f
  float* ktok1 = vtok0 + 8388608;              // 2097152 f
  float* vtok1 = ktok1 + 2097152;              // 2097152 f
  float* ktok2 = vtok1 + 2097152;              // 524288 f
  float* vtok2 = ktok2 + 524288;               // 524288 f

  const size_t needA = (size_t)(4194304 + 22020096) * 4;  // 104,857,600 B

  if (ws_size >= needA){
    hipLaunchKernelGGL(k_pre2, dim3(1280), dim3(256), 0, stream,
                       k1, v1, k2, v2, ktok1, vtok1, ktok2, vtok2);
    hipLaunchKernelGGL(k_cm,   dim3(4096), dim3(256), 0, stream,
                       q2, k2, v2, ktok2, vtok2, q1, ktok1, vtok1,
                       msg0, msg1, topk1);
    hipLaunchKernelGGL(k_tr0,  dim3(4096), dim3(256), 0, stream,
                       k0, v0, ktok0, vtok0);
    hipLaunchKernelGGL(k_fine<true>, dim3(32768), dim3(256), 0, stream,
                       q0, k0, v0, ktok0, vtok0, topk1, msg0, msg1, wv, out);
  } else {
    hipLaunchKernelGGL(k_coarse_fb,   dim3(4096),  dim3(256), 0, stream, q2,k2,v2, msg0, topk0);
    hipLaunchKernelGGL(k_mid_fb,      dim3(8192),  dim3(256), 0, stream,
                       q1,k1,v1, topk0, msg1, topk1);
    hipLaunchKernelGGL(k_fine<false>, dim3(32768), dim3(256), 0, stream,
                       q0,k0,v0, (float*)d_ws,(float*)d_ws, topk1, msg0, msg1, wv, out);
  }
}